// Round 4
// baseline (858.592 us; speedup 1.0000x reference)
//
#include <hip/hip_runtime.h>
#include <hip/hip_bf16.h>

typedef _Float16 half8 __attribute__((ext_vector_type(8)));
typedef float f32x4 __attribute__((ext_vector_type(4)));

#define SS 200
#define HH 128
#define NHD 4
#define FH 512
#define NEGF (-4294967295.0f)

// ---------------- pre-kernel: W1 [128][512] f32 -> fp16, MFMA-B-fragment-linear ----------------
// element ((nt*4 + ks)*64 + lane)*8 + j  holds  W1[ks*32 + (lane>>4)*8 + j][nt*16 + (lane&15)]
// Confirmed correct by R3 pass (absmax 1.95e-3): guide C/D map (row=q*4+r, col=c) is the true map.
__global__ void swizzle_w1(const float* __restrict__ W1, _Float16* __restrict__ dst) {
    int tid = blockIdx.x * blockDim.x + threadIdx.x;   // 0..65535
    int j    = tid & 7;
    int lane = (tid >> 3) & 63;
    int ks   = (tid >> 9) & 3;
    int nt   = tid >> 11;
    int k = ks * 32 + (lane >> 4) * 8 + j;
    int n = nt * 16 + (lane & 15);
    dst[tid] = (_Float16)W1[k * FH + n];
}

__device__ __forceinline__ float tanh_fast(float x) {
    x = fminf(fmaxf(x, -15.0f), 15.0f);
    float e = __expf(x + x);
    return (e - 1.0f) * __builtin_amdgcn_rcpf(e + 1.0f);
}

__device__ __forceinline__ f32x4 mfma16(half8 a, half8 b, f32x4 c) {
    return __builtin_amdgcn_mfma_f32_16x16x32_f16(a, b, c, 0, 0, 0);
}

// one group of NT m-tiles, this wave's 8 n-tiles.
// B-fragments stream from global (L2-resident 128 KB, shared by all blocks) with 1-deep prefetch.
template<int NT, bool USE_WS>
__device__ __forceinline__ void process_group(
    int mstart, const float* __restrict__ xb, const float* __restrict__ pos,
    const half8* __restrict__ w1g, const float* __restrict__ W1,
    const float4* w2s, float* attw,
    int wave, int lane, int q, int c)
{
    // --- A fragments: x+pos -> fp16; A[m = tile*16 + c][k = ks*32 + q*8 + j] ---
    half8 af[NT][4];
#pragma unroll
    for (int t = 0; t < NT; ++t) {
        int row = (mstart + t) * 16 + c;
        bool ok = row < SS;
        const float4* xr = (const float4*)(xb + row * HH);
        const float4* pr = (const float4*)(pos + row * HH);
#pragma unroll
        for (int ks = 0; ks < 4; ++ks) {
            int ci = ks * 8 + q * 2;
            float4 x0, x1, p0, p1;
            if (ok) { x0 = xr[ci]; x1 = xr[ci + 1]; p0 = pr[ci]; p1 = pr[ci + 1]; }
            else {
                x0 = make_float4(0.f,0.f,0.f,0.f); x1 = x0; p0 = x0; p1 = x0;
            }
            half8 h;
            h[0] = (_Float16)(x0.x + p0.x); h[1] = (_Float16)(x0.y + p0.y);
            h[2] = (_Float16)(x0.z + p0.z); h[3] = (_Float16)(x0.w + p0.w);
            h[4] = (_Float16)(x1.x + p1.x); h[5] = (_Float16)(x1.y + p1.y);
            h[6] = (_Float16)(x1.z + p1.z); h[7] = (_Float16)(x1.w + p1.w);
            af[t][ks] = h;
        }
    }

    float attp[NT][4][NHD];
#pragma unroll
    for (int t = 0; t < NT; ++t)
#pragma unroll
        for (int r = 0; r < 4; ++r)
#pragma unroll
            for (int k = 0; k < NHD; ++k) attp[t][r][k] = 0.0f;

    int nt0 = wave * 8, nt1 = nt0 + 8;

    half8 bf[4];
#pragma unroll
    for (int ks = 0; ks < 4; ++ks) {
        if (USE_WS) bf[ks] = w1g[(nt0 * 4 + ks) * 64 + lane];
        else {
#pragma unroll
            for (int j = 0; j < 8; ++j)
                bf[ks][j] = (_Float16)W1[(ks * 32 + q * 8 + j) * FH + nt0 * 16 + c];
        }
    }

    for (int nt = nt0; nt < nt1; ++nt) {
        // prefetch next B-fragment set: sits in flight under this tile's MFMA+epilogue
        half8 bfn[4];
        if (nt + 1 < nt1) {
#pragma unroll
            for (int ks = 0; ks < 4; ++ks) {
                if (USE_WS) bfn[ks] = w1g[((nt + 1) * 4 + ks) * 64 + lane];
                else {
#pragma unroll
                    for (int j = 0; j < 8; ++j)
                        bfn[ks][j] = (_Float16)W1[(ks * 32 + q * 8 + j) * FH + (nt + 1) * 16 + c];
                }
            }
        }
        float4 w2v = w2s[nt * 16 + c];          // W2[f][0..3], f = nt*16 + c
        f32x4 acc[NT];
#pragma unroll
        for (int t = 0; t < NT; ++t) { f32x4 z = {0.f,0.f,0.f,0.f}; acc[t] = z; }
#pragma unroll
        for (int ks = 0; ks < 4; ++ks)
#pragma unroll
            for (int t = 0; t < NT; ++t)
                acc[t] = mfma16(af[t][ks], bf[ks], acc[t]);
        // C/D map (confirmed): element r of lane holds hidden[tile*16 + q*4+r][nt*16 + c]
#pragma unroll
        for (int t = 0; t < NT; ++t)
#pragma unroll
            for (int r = 0; r < 4; ++r) {
                float h = tanh_fast(acc[t][r]);
                attp[t][r][0] += h * w2v.x;
                attp[t][r][1] += h * w2v.y;
                attp[t][r][2] += h * w2v.z;
                attp[t][r][3] += h * w2v.w;
            }
#pragma unroll
        for (int ks = 0; ks < 4; ++ks) bf[ks] = bfn[ks];
    }

    // sum over the 16 f-columns (c-slots) of this quad, accumulate into shared att
#pragma unroll
    for (int t = 0; t < NT; ++t)
#pragma unroll
        for (int r = 0; r < 4; ++r)
#pragma unroll
            for (int k = 0; k < NHD; ++k) {
                float v = attp[t][r][k];
                v += __shfl_xor(v, 1);
                v += __shfl_xor(v, 2);
                v += __shfl_xor(v, 4);
                v += __shfl_xor(v, 8);
                if (c == 0)
                    atomicAdd(&attw[((mstart + t) * 16 + q * 4 + r) * NHD + k], v);
            }
}

template<bool USE_WS>
__global__ __launch_bounds__(256, 3)
void mhan_main(const float* __restrict__ item, const int* __restrict__ mask,
               const float* __restrict__ pos, const float* __restrict__ W1,
               const float* __restrict__ W2, const _Float16* __restrict__ w1sw,
               float* __restrict__ out)
{
    __shared__ float4 w2s[FH];                // 8192 B
    __shared__ float  attw[208 * NHD];        // 3328 B   (total ~11.5 KB -> LDS never binds)

    int tid = threadIdx.x;
    int b   = blockIdx.x;
    int lane = tid & 63, wave = tid >> 6;
    int q = lane >> 4, c = lane & 15;

    for (int i = tid; i < FH; i += 256) w2s[i] = ((const float4*)W2)[i];
    for (int i = tid; i < 208 * NHD; i += 256) attw[i] = 0.0f;
    __syncthreads();

    const float* xb = item + (size_t)b * SS * HH;
    const half8* w1g = (const half8*)w1sw;

    process_group<4, USE_WS>(0,  xb, pos, w1g, W1, w2s, attw, wave, lane, q, c);
    process_group<3, USE_WS>(4,  xb, pos, w1g, W1, w2s, attw, wave, lane, q, c);
    process_group<3, USE_WS>(7,  xb, pos, w1g, W1, w2s, attw, wave, lane, q, c);
    process_group<3, USE_WS>(10, xb, pos, w1g, W1, w2s, attw, wave, lane, q, c);
    __syncthreads();

    // ---- masked softmax over S; head k = wave ----
    {
        int k = wave;
        float l[4];
        float m = -__builtin_inff();
#pragma unroll
        for (int i = 0; i < 4; ++i) {
            int s = lane + i * 64;
            if (s < SS) {
                float lv = (mask[(size_t)b * SS + s] != 0) ? attw[s * NHD + k] : NEGF;
                l[i] = lv;
                m = fmaxf(m, lv);
            } else {
                l[i] = -__builtin_inff();
            }
        }
#pragma unroll
        for (int off = 32; off >= 1; off >>= 1) m = fmaxf(m, __shfl_xor(m, off));
        float e[4], sum = 0.0f;
#pragma unroll
        for (int i = 0; i < 4; ++i) {
            e[i] = (l[i] == -__builtin_inff()) ? 0.0f : __expf(l[i] - m);
            sum += e[i];
        }
#pragma unroll
        for (int off = 32; off >= 1; off >>= 1) sum += __shfl_xor(sum, off);
        float inv = __builtin_amdgcn_rcpf(sum);
#pragma unroll
        for (int i = 0; i < 4; ++i) {
            int s = lane + i * 64;
            if (s < SS) attw[s * NHD + k] = e[i] * inv;
        }
    }
    // wave k wrote only column k and reads only column k below — same-wave DS ordering suffices

    // ---- interest[k][h] = sum_s w[s,k] * x[s,h]  (fp32 out) ----
    {
        int k = wave;
        float ax = 0.0f, ay = 0.0f;
#pragma unroll 8
        for (int s = 0; s < SS; ++s) {
            float w = attw[s * NHD + k];
            float2 xv = ((const float2*)(xb + s * HH))[lane];
            ax += w * xv.x;
            ay += w * xv.y;
        }
        size_t o = ((size_t)b * NHD + k) * HH + lane * 2;
        float2 ov; ov.x = ax; ov.y = ay;
        *(float2*)(out + o) = ov;
    }
}

extern "C" void kernel_launch(void* const* d_in, const int* in_sizes, int n_in,
                              void* d_out, int out_size, void* d_ws, size_t ws_size,
                              hipStream_t stream) {
    const float* item = (const float*)d_in[0];
    const int*   mask = (const int*)d_in[1];
    const float* pos  = (const float*)d_in[2];
    const float* W1   = (const float*)d_in[3];
    const float* W2   = (const float*)d_in[4];
    float* out = (float*)d_out;

    int B = in_sizes[0] / (SS * HH);
    bool use_ws = ws_size >= (size_t)(HH * FH * sizeof(_Float16));

    if (use_ws) {
        hipLaunchKernelGGL(swizzle_w1, dim3((HH * FH) / 256), dim3(256), 0, stream,
                           W1, (_Float16*)d_ws);
        hipLaunchKernelGGL((mhan_main<true>), dim3(B), dim3(256), 0, stream,
                           item, mask, pos, W1, W2, (const _Float16*)d_ws, out);
    } else {
        hipLaunchKernelGGL((mhan_main<false>), dim3(B), dim3(256), 0, stream,
                           item, mask, pos, W1, W2, (const _Float16*)nullptr, out);
    }
}